// Round 10
// baseline (586.464 us; speedup 1.0000x reference)
//
#include <hip/hip_runtime.h>
#include <hip/hip_bf16.h>

// Problem constants: B=4, S=2048, HID=128, NH=8, D_MODEL=1024
#define SEQ 2048
#define NBATCH 4
#define NHEAD 8
#define HDIM 128

typedef __attribute__((ext_vector_type(8))) short bf16x8;
typedef __attribute__((ext_vector_type(4))) float f32x4;
typedef __attribute__((ext_vector_type(4))) _Float16 f16x4;
typedef __attribute__((ext_vector_type(2))) __fp16 h16x2;   // builtin cvt_pkrtz type
typedef long i64;
typedef unsigned long long u64;

static __device__ __forceinline__ short f2b(float f) {
  union { float f; unsigned u; } v; v.f = f;
  unsigned r = (v.u + 0x7FFFu + ((v.u >> 16) & 1u)) >> 16;
  return (short)(unsigned short)r;
}
static __device__ __forceinline__ float b2f(short b) {
  union { unsigned u; float f; } v; v.u = ((unsigned)(unsigned short)b) << 16;
  return v.f;
}
// OCP e4m3fn encode (software fallback), RTN-even, saturate at 448.
static __device__ __forceinline__ unsigned f2e4m3(float x) {
  union { float f; unsigned u; } v; v.f = x;
  unsigned s = (v.u >> 24) & 0x80u;
  unsigned a = v.u & 0x7FFFFFFFu;
  if (a > 0x43E00000u) a = 0x43E00000u;
  if (a < 0x3C800000u) {
    union { unsigned u; float f; } w; w.u = a;
    return s | (unsigned)(int)(w.f * 512.0f + 0.5f);
  }
  a += 0x7FFFFu + ((a >> 20) & 1u);
  return s | (((a >> 23) - 120u) << 3) | ((a >> 20) & 7u);
}

#if defined(__has_builtin)
#if __has_builtin(__builtin_amdgcn_cvt_pk_fp8_f32)
#define HAVE_HW_FP8 1
#endif
#endif
static __device__ __forceinline__ unsigned cvt_pk_fp8(float a, float b) {
#ifdef HAVE_HW_FP8
  return (unsigned)__builtin_amdgcn_cvt_pk_fp8_f32(a, b, 0, false) & 0xFFFFu;
#else
  return f2e4m3(a) | (f2e4m3(b) << 8);
#endif
}
static __device__ __forceinline__ unsigned cvt_fp8_1(float a) {
  return cvt_pk_fp8(a, 0.0f) & 0xFFu;
}
// pack two __fp16x2 (from cvt_pkrtz) into one _Float16x4 MFMA fragment (bit-pun)
static __device__ __forceinline__ f16x4 pack4h(h16x2 lo, h16x2 hi) {
  union { h16x2 a[2]; f16x4 b; } u;
  u.a[0] = lo; u.a[1] = hi;
  return u.b;
}

// ---------------- 1) x fp32 -> bf16 ----------------
__global__ __launch_bounds__(256) void k_cvt_x(const float* __restrict__ x,
                                               short* __restrict__ xb) {
  int i = blockIdx.x * blockDim.x + threadIdx.x;
  const float4* p = reinterpret_cast<const float4*>(x) + (size_t)i * 2;
  float4 a = p[0], c = p[1];
  bf16x8 o;
  o[0] = f2b(a.x); o[1] = f2b(a.y); o[2] = f2b(a.z); o[3] = f2b(a.w);
  o[4] = f2b(c.x); o[5] = f2b(c.y); o[6] = f2b(c.z); o[7] = f2b(c.w);
  reinterpret_cast<bf16x8*>(xb)[i] = o;
}

// ---------------- 2) W_qkv [128][3072] -> Wqt bf16 [3072][128] ----------------
__global__ __launch_bounds__(256) void k_wqkv(const float* __restrict__ w,
                                              short* __restrict__ wt) {
  int tid = blockIdx.x * blockDim.x + threadIdx.x;
  int k = tid & 127, j = tid >> 7;
  wt[tid] = f2b(w[(size_t)k * 3072 + j]);
}

// ---------------- 3) W_o [1024][128] -> Wot bf16 [128][1024] ----------------
__global__ __launch_bounds__(256) void k_wo(const float* __restrict__ w,
                                            short* __restrict__ wt) {
  int tid = blockIdx.x * blockDim.x + threadIdx.x;
  int k = tid & 1023, c = tid >> 10;
  wt[tid] = f2b(w[(size_t)k * 128 + c]);
}

// ---------------- 4) QKV GEMM -> Qf,Kf fp8 (x4) [bh][s][c]; Vb bf16 [bh][t][c] -
__global__ __launch_bounds__(256) void k_qkv(const short* __restrict__ xb,
                                             const short* __restrict__ wqt,
                                             const float* __restrict__ bias,
                                             unsigned char* __restrict__ Qf,
                                             unsigned char* __restrict__ Kf,
                                             short* __restrict__ Vb) {
  int wave = threadIdx.x >> 6, lane = threadIdx.x & 63;
  int lr = lane & 15, lg = lane >> 4;
  int m0 = blockIdx.y * 64 + wave * 16;
  int j0 = blockIdx.x * 128;

  bf16x8 a[4];
#pragma unroll
  for (int ks = 0; ks < 4; ++ks)
    a[ks] = *reinterpret_cast<const bf16x8*>(xb + (size_t)(m0 + lr) * 128 + ks * 32 + lg * 8);

  f32x4 acc[8];
#pragma unroll
  for (int nf = 0; nf < 8; ++nf) acc[nf] = (f32x4){0.f, 0.f, 0.f, 0.f};

#pragma unroll
  for (int ks = 0; ks < 4; ++ks) {
#pragma unroll
    for (int nf = 0; nf < 8; ++nf) {
      bf16x8 bfr = *reinterpret_cast<const bf16x8*>(
          wqt + (size_t)(j0 + nf * 16 + lr) * 128 + ks * 32 + lg * 8);
      acc[nf] = __builtin_amdgcn_mfma_f32_16x16x32_bf16(a[ks], bfr, acc[nf], 0, 0, 0);
    }
  }

  int bb = m0 >> 11;
  int sbase = m0 & 2047;
#pragma unroll
  for (int nf = 0; nf < 8; ++nf) {
    int j = j0 + nf * 16 + lr;
    float bv = bias[j];
    int sel = j >> 10;
    int jj = j & 1023;
    int h = jj >> 7, c = jj & 127;
    size_t bh = (size_t)(bb * NHEAD + h);
    if (sel == 2) {
#pragma unroll
      for (int r = 0; r < 4; ++r) {
        int s = sbase + lg * 4 + r;
        Vb[(bh * SEQ + s) * HDIM + c] = f2b(acc[nf][r] + bv);
      }
    } else {
      unsigned char* dst = (sel ? Kf : Qf);
#pragma unroll
      for (int r = 0; r < 4; ++r) {
        int s = sbase + lg * 4 + r;
        dst[(bh * SEQ + s) * HDIM + c] = (unsigned char)cvt_fp8_1((acc[nf][r] + bv) * 4.0f);
      }
    }
  }
}

// ---------------- 5) VW = V @ W_o[head] -> f16, tiled [bh][t/16][c][16] --------
// A = Wot slice (rows c, k contiguous), B = Vb (col t, k contiguous), 16x16x32 bf16.
__global__ __launch_bounds__(256) void k_vw(const short* __restrict__ wot,
                                            const short* __restrict__ Vb,
                                            _Float16* __restrict__ VWf) {
  int w = threadIdx.x >> 6, lane = threadIdx.x & 63, lr = lane & 15, lg = lane >> 4;
  int bh = blockIdx.y, h = bh & 7;
  int tile = blockIdx.x * 4 + w;
  int t0 = tile * 16;

  f32x4 acc[8];
#pragma unroll
  for (int cf = 0; cf < 8; ++cf) acc[cf] = (f32x4){0.f, 0.f, 0.f, 0.f};

#pragma unroll
  for (int ks = 0; ks < 4; ++ks) {
    bf16x8 bfr = *reinterpret_cast<const bf16x8*>(
        Vb + ((size_t)bh * SEQ + t0 + lr) * HDIM + ks * 32 + lg * 8);
#pragma unroll
    for (int cf = 0; cf < 8; ++cf) {
      bf16x8 af = *reinterpret_cast<const bf16x8*>(
          wot + (size_t)(cf * 16 + lr) * 1024 + h * 128 + ks * 32 + lg * 8);
      acc[cf] = __builtin_amdgcn_mfma_f32_16x16x32_bf16(af, bfr, acc[cf], 0, 0, 0);
    }
  }
  // D[c_local=4lg+r][t_local=lr] -> VWf[((bh*128+tile)*128 + c)*16 + t_local]
  _Float16* dst = VWf + ((size_t)bh * 128 + tile) * 128 * 16;
#pragma unroll
  for (int cf = 0; cf < 8; ++cf)
#pragma unroll
    for (int r = 0; r < 4; ++r)
      dst[(size_t)(cf * 16 + 4 * lg + r) * 16 + lr] = (_Float16)acc[cf][r];
}

// ---------------- 6) Totv[bh][k] = sum_t Vb ------------------------------------
__global__ __launch_bounds__(256) void k_tot(const short* __restrict__ Vb,
                                             float* __restrict__ Totv) {
  __shared__ float sh[16][128];
  int bh = blockIdx.x;
  int i = threadIdx.x & 15, g = threadIdx.x >> 4;
  const short* p = Vb + (size_t)bh * SEQ * HDIM + i * 8;
  float s[8] = {0, 0, 0, 0, 0, 0, 0, 0};
  for (int r = g; r < SEQ; r += 16) {
    bf16x8 v = *reinterpret_cast<const bf16x8*>(p + (size_t)r * HDIM);
#pragma unroll
    for (int j = 0; j < 8; ++j) s[j] += b2f(v[j]);
  }
#pragma unroll
  for (int j = 0; j < 8; ++j) sh[g][i * 8 + j] = s[j];
  __syncthreads();
  if (threadIdx.x < 128) {
    float t = 0;
#pragma unroll
    for (int g2 = 0; g2 < 16; ++g2) t += sh[g2][threadIdx.x];
    Totv[bh * 128 + threadIdx.x] = t;
  }
}

// ---------------- 7) Totw[b][c] = (1/8) sum_{h,k} Totv * W_o --------------------
__global__ __launch_bounds__(256) void k_totw(const float* __restrict__ Totv,
                                              const float* __restrict__ wo,
                                              float* __restrict__ Totw) {
  __shared__ float sh[128];
  int b = blockIdx.x, c = threadIdx.x & 127, h2 = threadIdx.x >> 7;
  float s = 0.f;
  for (int j = h2 * 512; j < h2 * 512 + 512; ++j)
    s += Totv[b * 1024 + j] * wo[(size_t)j * 128 + c];
  if (h2) sh[c] = s;
  __syncthreads();
  if (!h2) Totw[b * 128 + c] = 0.125f * (s + sh[c]);
}

// ---------------- 8) Attention: barrier-free, LDS-free, 8 heads per wave -------
// S^T = mfma(K, Q): lane(lr,lg) holds S[s=lr][t=4lg+r] per head -> softmax across
// heads is register-local. PV = mfma_16x16x16f16(VW^T, P^T): B-frag k=4lg+j
// matches S^T layout exactly (no shuffles). Output = dev@W_o partials (fp8 x8).
// grid 512 x 256thr (4 waves). xcd=bid&7: b=xcd>>1, tcA=xcd&1; slot=bid>>3:
// tcB=slot&3, q=slot>>2; tc=(tcB<<1)|tcA in [0,8); wave w: phases st=4q+w, 127-st.
__global__ __launch_bounds__(256, 2) void k_attn(const unsigned char* __restrict__ Qf,
                                                 const unsigned char* __restrict__ Kf,
                                                 const _Float16* __restrict__ VWf,
                                                 unsigned char* __restrict__ Part) {
  int tid = threadIdx.x;
  int w = tid >> 6, lane = tid & 63, lr = lane & 15, lg = lane >> 4;
  int bid = blockIdx.x;
  int xcd = bid & 7, slot = bid >> 3;
  int b = xcd >> 1, tcA = xcd & 1;
  int tcB = slot & 3, q = slot >> 2;
  int tc = (tcB << 1) | tcA;
  const float SC = 0.001953125f;  // 1/(16*32): undo Q*4,K*4 and /sqrt(1024)
  const size_t BH = (size_t)SEQ * HDIM;

#pragma unroll 1
  for (int ph = 0; ph < 2; ++ph) {
    int st = ph ? (127 - (q * 4 + w)) : (q * 4 + w);
    int rb = st * 16;

    // Q B-frags (col=s=rb+lr, k contiguous), all 8 heads, held across loop
    i64 qa[8][4];
#pragma unroll
    for (int h = 0; h < 8; ++h)
#pragma unroll
      for (int ks = 0; ks < 4; ++ks)
        qa[h][ks] = *reinterpret_cast<const i64*>(
            Qf + (size_t)(b * 8 + h) * BH + (size_t)(rb + lr) * HDIM + ks * 32 + lg * 8);

    f32x4 oa[8];
#pragma unroll
    for (int cf = 0; cf < 8; ++cf) oa[cf] = (f32x4){0.f, 0.f, 0.f, 0.f};

    int ttF = 120 + tc;
#pragma unroll 1
    for (int tt = ttF; tt >= st; tt -= 8) {
      int t0 = tt * 16;
      // ---- QK^T (swapped): S[h] = K_tile x Q_tile, D[t][s] ----
      f32x4 S[8];
#pragma unroll
      for (int h = 0; h < 8; ++h) {
        const unsigned char* Kh = Kf + (size_t)(b * 8 + h) * BH + (size_t)(t0 + lr) * HDIM;
        f32x4 s = (f32x4){0.f, 0.f, 0.f, 0.f};
#pragma unroll
        for (int ks = 0; ks < 4; ++ks) {
          i64 kfr = *reinterpret_cast<const i64*>(Kh + ks * 32 + lg * 8);
          s = __builtin_amdgcn_mfma_f32_16x16x32_fp8_fp8(kfr, qa[h][ks], s, 0, 0, 0);
        }
        S[h] = s;
      }
      // ---- cross-head softmax: fully in-register ----
      f16x4 P[8];
      {
        float ex[8][4];
        float sm0 = 0.f, sm1 = 0.f, sm2 = 0.f, sm3 = 0.f;
#pragma unroll
        for (int h = 0; h < 8; ++h) {
          ex[h][0] = __expf(S[h][0] * SC); sm0 += ex[h][0];
          ex[h][1] = __expf(S[h][1] * SC); sm1 += ex[h][1];
          ex[h][2] = __expf(S[h][2] * SC); sm2 += ex[h][2];
          ex[h][3] = __expf(S[h][3] * SC); sm3 += ex[h][3];
        }
        int sg = rb + lr;
        int tb = t0 + 4 * lg;
        float i0 = 8.0f / sm0, i1 = 8.0f / sm1, i2 = 8.0f / sm2, i3 = 8.0f / sm3;
        bool m0 = (tb >= sg), m1 = (tb + 1 >= sg), m2 = (tb + 2 >= sg), m3 = (tb + 3 >= sg);
#pragma unroll
        for (int h = 0; h < 8; ++h) {
          float p0 = m0 ? ex[h][0] * i0 - 1.0f : 0.0f;
          float p1 = m1 ? ex[h][1] * i1 - 1.0f : 0.0f;
          float p2 = m2 ? ex[h][2] * i2 - 1.0f : 0.0f;
          float p3 = m3 ? ex[h][3] * i3 - 1.0f : 0.0f;
          P[h] = pack4h(__builtin_amdgcn_cvt_pkrtz(p0, p1),
                        __builtin_amdgcn_cvt_pkrtz(p2, p3));
        }
      }
      // ---- PV: oa[cf] += VW^T x P^T  (16x16x16 f16, K=t-tile of 16) ----
#pragma unroll
      for (int h = 0; h < 8; ++h) {
        const _Float16* VWh = VWf + ((size_t)(b * 8 + h) * 128 + tt) * (128 * 16);
#pragma unroll
        for (int cf = 0; cf < 8; ++cf) {
          f16x4 vw = *reinterpret_cast<const f16x4*>(VWh + (size_t)(cf * 16 + lr) * 16 + 4 * lg);
          oa[cf] = __builtin_amdgcn_mfma_f32_16x16x16f16(vw, P[h], oa[cf], 0, 0, 0);
        }
      }
    }

    // flush: D[c_local=4lg+r][s_local=lr]; oa = 8*dev_slot; Part = dev_slot*32
    unsigned char* Pt = Part + (size_t)tc * ((size_t)4 * SEQ * 128) +
                        ((size_t)(b * SEQ + rb + lr)) * 128;
#pragma unroll
    for (int cf = 0; cf < 8; ++cf) {
      unsigned u = cvt_pk_fp8(oa[cf][0] * 4.0f, oa[cf][1] * 4.0f) |
                   (cvt_pk_fp8(oa[cf][2] * 4.0f, oa[cf][3] * 4.0f) << 16);
      *reinterpret_cast<unsigned*>(Pt + cf * 16 + lg * 4) = u;
    }
  }
}

// ---------------- 9) Finish: out = sum(Part)/32 + Totw + b_o (fp32) ------------
__global__ __launch_bounds__(256) void k_fin(const unsigned char* __restrict__ Part,
                                             const float* __restrict__ Totw,
                                             const float* __restrict__ bo,
                                             float* __restrict__ out) {
  __shared__ float lut[256];
  {
    int t = threadIdx.x;
    unsigned e = (t >> 3) & 15u, m = t & 7u;
    float mag = e ? ldexpf((float)(8 + m), (int)e - 10) : ldexpf((float)m, -9);
    lut[t] = (t & 128) ? -mag : mag;
  }
  __syncthreads();
  const size_t PSZ = (size_t)4 * SEQ * 128;
  int idx = blockIdx.x * 256 + threadIdx.x;  // 1M elements
  int c = idx & 127, sg = idx >> 7;
  int b = sg >> 11;
  float s = 0.f;
#pragma unroll
  for (int t = 0; t < 8; ++t) s += lut[Part[(size_t)t * PSZ + (size_t)sg * 128 + c]];
  out[(size_t)sg * 128 + c] = s * 0.03125f + Totw[b * 128 + c] + bo[c];
}

extern "C" void kernel_launch(void* const* d_in, const int* in_sizes, int n_in,
                              void* d_out, int out_size, void* d_ws, size_t ws_size,
                              hipStream_t stream) {
  const float* x    = (const float*)d_in[0];
  const float* wqkv = (const float*)d_in[1];
  const float* bqkv = (const float*)d_in[2];
  const float* wo   = (const float*)d_in[3];
  const float* bo   = (const float*)d_in[4];

  char* ws = (char*)d_ws;
  const size_t MB = (size_t)1 << 20;
  short* xb           = (short*)(ws + 0);               //  2 MB : x bf16
  short* wqt          = (short*)(ws + 2 * MB);          // .75MB : W_qkv^T bf16
  short* wot          = (short*)(ws + 3 * MB);          // .25MB : W_o^T bf16
  unsigned char* Qf   = (unsigned char*)(ws + 4 * MB);  //  8 MB fp8 [bh][s][c]
  unsigned char* Kf   = (unsigned char*)(ws + 12 * MB); //  8 MB fp8 [bh][t][c]
  short* Vb           = (short*)(ws + 20 * MB);         // 16 MB bf16 [bh][t][c]
  _Float16* VWf       = (_Float16*)(ws + 36 * MB);      // 16 MB f16 [bh][t/16][c][16]
  float* Totv         = (float*)(ws + 52 * MB);         // 16 KB
  float* Totw         = (float*)(ws + 53 * MB);         //  2 KB
  unsigned char* Part = (unsigned char*)(ws + 54 * MB); //  8 MB fp8 x8 partials

  hipLaunchKernelGGL(k_cvt_x, dim3(512), dim3(256), 0, stream, x, xb);
  hipLaunchKernelGGL(k_wqkv, dim3(1536), dim3(256), 0, stream, wqkv, wqt);
  hipLaunchKernelGGL(k_wo, dim3(512), dim3(256), 0, stream, wo, wot);
  hipLaunchKernelGGL(k_qkv, dim3(24, 128), dim3(256), 0, stream, xb, wqt, bqkv, Qf, Kf, Vb);
  hipLaunchKernelGGL(k_vw, dim3(32, 32), dim3(256), 0, stream, wot, Vb, VWf);
  hipLaunchKernelGGL(k_tot, dim3(32), dim3(256), 0, stream, Vb, Totv);
  hipLaunchKernelGGL(k_totw, dim3(4), dim3(256), 0, stream, Totv, wo, Totw);
  hipLaunchKernelGGL(k_attn, dim3(512), dim3(256), 0, stream, Qf, Kf, VWf, Part);
  hipLaunchKernelGGL(k_fin, dim3(4096), dim3(256), 0, stream, Part, Totw, bo, (float*)d_out);
}

// Round 11
// 376.970 us; speedup vs baseline: 1.5557x; 1.5557x over previous
//
#include <hip/hip_runtime.h>
#include <hip/hip_bf16.h>

// Problem constants: B=4, S=2048, HID=128, NH=8, D_MODEL=1024
#define SEQ 2048
#define NBATCH 4
#define NHEAD 8
#define HDIM 128

typedef __attribute__((ext_vector_type(8))) short bf16x8;
typedef __attribute__((ext_vector_type(4))) float f32x4;
typedef __attribute__((ext_vector_type(4))) _Float16 f16x4;
typedef __attribute__((ext_vector_type(2))) __fp16 h16x2;   // builtin cvt_pkrtz type
typedef long i64;
typedef unsigned long long u64;

static __device__ __forceinline__ short f2b(float f) {
  union { float f; unsigned u; } v; v.f = f;
  unsigned r = (v.u + 0x7FFFu + ((v.u >> 16) & 1u)) >> 16;
  return (short)(unsigned short)r;
}
static __device__ __forceinline__ float b2f(short b) {
  union { unsigned u; float f; } v; v.u = ((unsigned)(unsigned short)b) << 16;
  return v.f;
}
// OCP e4m3fn encode (software fallback), RTN-even, saturate at 448.
static __device__ __forceinline__ unsigned f2e4m3(float x) {
  union { float f; unsigned u; } v; v.f = x;
  unsigned s = (v.u >> 24) & 0x80u;
  unsigned a = v.u & 0x7FFFFFFFu;
  if (a > 0x43E00000u) a = 0x43E00000u;
  if (a < 0x3C800000u) {
    union { unsigned u; float f; } w; w.u = a;
    return s | (unsigned)(int)(w.f * 512.0f + 0.5f);
  }
  a += 0x7FFFFu + ((a >> 20) & 1u);
  return s | (((a >> 23) - 120u) << 3) | ((a >> 20) & 7u);
}

#if defined(__has_builtin)
#if __has_builtin(__builtin_amdgcn_cvt_pk_fp8_f32)
#define HAVE_HW_FP8 1
#endif
#endif
static __device__ __forceinline__ unsigned cvt_pk_fp8(float a, float b) {
#ifdef HAVE_HW_FP8
  return (unsigned)__builtin_amdgcn_cvt_pk_fp8_f32(a, b, 0, false) & 0xFFFFu;
#else
  return f2e4m3(a) | (f2e4m3(b) << 8);
#endif
}
static __device__ __forceinline__ unsigned cvt_fp8_1(float a) {
  return cvt_pk_fp8(a, 0.0f) & 0xFFu;
}
// pack two __fp16x2 (from cvt_pkrtz) into one _Float16x4 MFMA fragment (bit-pun)
static __device__ __forceinline__ f16x4 pack4h(h16x2 lo, h16x2 hi) {
  union { h16x2 a[2]; f16x4 b; } u;
  u.a[0] = lo; u.a[1] = hi;
  return u.b;
}
static __device__ __forceinline__ f16x4 as_f16x4(i64 x) {
  union { i64 l; f16x4 v; } u; u.l = x; return u.v;
}

// ---------------- 1) x fp32 -> bf16 ----------------
__global__ __launch_bounds__(256) void k_cvt_x(const float* __restrict__ x,
                                               short* __restrict__ xb) {
  int i = blockIdx.x * blockDim.x + threadIdx.x;
  const float4* p = reinterpret_cast<const float4*>(x) + (size_t)i * 2;
  float4 a = p[0], c = p[1];
  bf16x8 o;
  o[0] = f2b(a.x); o[1] = f2b(a.y); o[2] = f2b(a.z); o[3] = f2b(a.w);
  o[4] = f2b(c.x); o[5] = f2b(c.y); o[6] = f2b(c.z); o[7] = f2b(c.w);
  reinterpret_cast<bf16x8*>(xb)[i] = o;
}

// ---------------- 2) W_qkv [128][3072] -> Wqt bf16 [3072][128] ----------------
__global__ __launch_bounds__(256) void k_wqkv(const float* __restrict__ w,
                                              short* __restrict__ wt) {
  int tid = blockIdx.x * blockDim.x + threadIdx.x;
  int k = tid & 127, j = tid >> 7;
  wt[tid] = f2b(w[(size_t)k * 3072 + j]);
}

// ---------------- 3) W_o [1024][128] -> Wot bf16 [128][1024] ----------------
__global__ __launch_bounds__(256) void k_wo(const float* __restrict__ w,
                                            short* __restrict__ wt) {
  int tid = blockIdx.x * blockDim.x + threadIdx.x;
  int k = tid & 1023, c = tid >> 10;
  wt[tid] = f2b(w[(size_t)k * 128 + c]);
}

// ---------------- 4) QKV GEMM -> Qf,Kf fp8 (x4) [bh][s][c]; Vb bf16 [bh][t][c] -
__global__ __launch_bounds__(256) void k_qkv(const short* __restrict__ xb,
                                             const short* __restrict__ wqt,
                                             const float* __restrict__ bias,
                                             unsigned char* __restrict__ Qf,
                                             unsigned char* __restrict__ Kf,
                                             short* __restrict__ Vb) {
  int wave = threadIdx.x >> 6, lane = threadIdx.x & 63;
  int lr = lane & 15, lg = lane >> 4;
  int m0 = blockIdx.y * 64 + wave * 16;
  int j0 = blockIdx.x * 128;

  bf16x8 a[4];
#pragma unroll
  for (int ks = 0; ks < 4; ++ks)
    a[ks] = *reinterpret_cast<const bf16x8*>(xb + (size_t)(m0 + lr) * 128 + ks * 32 + lg * 8);

  f32x4 acc[8];
#pragma unroll
  for (int nf = 0; nf < 8; ++nf) acc[nf] = (f32x4){0.f, 0.f, 0.f, 0.f};

#pragma unroll
  for (int ks = 0; ks < 4; ++ks) {
#pragma unroll
    for (int nf = 0; nf < 8; ++nf) {
      bf16x8 bfr = *reinterpret_cast<const bf16x8*>(
          wqt + (size_t)(j0 + nf * 16 + lr) * 128 + ks * 32 + lg * 8);
      acc[nf] = __builtin_amdgcn_mfma_f32_16x16x32_bf16(a[ks], bfr, acc[nf], 0, 0, 0);
    }
  }

  int bb = m0 >> 11;
  int sbase = m0 & 2047;
#pragma unroll
  for (int nf = 0; nf < 8; ++nf) {
    int j = j0 + nf * 16 + lr;
    float bv = bias[j];
    int sel = j >> 10;
    int jj = j & 1023;
    int h = jj >> 7, c = jj & 127;
    size_t bh = (size_t)(bb * NHEAD + h);
    if (sel == 2) {
#pragma unroll
      for (int r = 0; r < 4; ++r) {
        int s = sbase + lg * 4 + r;
        Vb[(bh * SEQ + s) * HDIM + c] = f2b(acc[nf][r] + bv);
      }
    } else {
      unsigned char* dst = (sel ? Kf : Qf);
#pragma unroll
      for (int r = 0; r < 4; ++r) {
        int s = sbase + lg * 4 + r;
        dst[(bh * SEQ + s) * HDIM + c] = (unsigned char)cvt_fp8_1((acc[nf][r] + bv) * 4.0f);
      }
    }
  }
}

// ---------------- 5) VW = V @ W_o[head] -> f16, tiled [bh][t/16][c][16] --------
__global__ __launch_bounds__(256) void k_vw(const short* __restrict__ wot,
                                            const short* __restrict__ Vb,
                                            _Float16* __restrict__ VWf) {
  int w = threadIdx.x >> 6, lane = threadIdx.x & 63, lr = lane & 15, lg = lane >> 4;
  int bh = blockIdx.y, h = bh & 7;
  int tile = blockIdx.x * 4 + w;
  int t0 = tile * 16;

  f32x4 acc[8];
#pragma unroll
  for (int cf = 0; cf < 8; ++cf) acc[cf] = (f32x4){0.f, 0.f, 0.f, 0.f};

#pragma unroll
  for (int ks = 0; ks < 4; ++ks) {
    bf16x8 bfr = *reinterpret_cast<const bf16x8*>(
        Vb + ((size_t)bh * SEQ + t0 + lr) * HDIM + ks * 32 + lg * 8);
#pragma unroll
    for (int cf = 0; cf < 8; ++cf) {
      bf16x8 af = *reinterpret_cast<const bf16x8*>(
          wot + (size_t)(cf * 16 + lr) * 1024 + h * 128 + ks * 32 + lg * 8);
      acc[cf] = __builtin_amdgcn_mfma_f32_16x16x32_bf16(af, bfr, acc[cf], 0, 0, 0);
    }
  }
  _Float16* dst = VWf + ((size_t)bh * 128 + tile) * 128 * 16;
#pragma unroll
  for (int cf = 0; cf < 8; ++cf)
#pragma unroll
    for (int r = 0; r < 4; ++r)
      dst[(size_t)(cf * 16 + 4 * lg + r) * 16 + lr] = (_Float16)acc[cf][r];
}

// ---------------- 6) Totp2[bh][slice][c] = sum over 256 rows of Vb -------------
__global__ __launch_bounds__(256) void k_tot(const short* __restrict__ Vb,
                                             float* __restrict__ Totp2) {
  __shared__ float sh[16][128];
  int bh = blockIdx.x, sl = blockIdx.y;
  int i = threadIdx.x & 15, g = threadIdx.x >> 4;
  const short* p = Vb + (size_t)bh * SEQ * HDIM + i * 8;
  float s[8] = {0, 0, 0, 0, 0, 0, 0, 0};
  for (int r = sl * 256 + g; r < sl * 256 + 256; r += 16) {
    bf16x8 v = *reinterpret_cast<const bf16x8*>(p + (size_t)r * HDIM);
#pragma unroll
    for (int j = 0; j < 8; ++j) s[j] += b2f(v[j]);
  }
#pragma unroll
  for (int j = 0; j < 8; ++j) sh[g][i * 8 + j] = s[j];
  __syncthreads();
  if (threadIdx.x < 128) {
    float t = 0;
#pragma unroll
    for (int g2 = 0; g2 < 16; ++g2) t += sh[g2][threadIdx.x];
    Totp2[(size_t)(bh * 8 + sl) * 128 + threadIdx.x] = t;
  }
}

// ---------------- 7) Totp[b][g][c] = sum_{j in g-range} Totv(j) * W_o[j][c] ----
__global__ __launch_bounds__(256) void k_totw(const float* __restrict__ Totp2,
                                              const float* __restrict__ wo,
                                              float* __restrict__ Totp) {
  __shared__ float sh[128];
  int b = blockIdx.x, g = blockIdx.y;       // grid (4,8)
  int c = threadIdx.x & 127, h2 = threadIdx.x >> 7;
  float s = 0.f;
  int j0 = g * 128 + h2 * 64;
  for (int j = j0; j < j0 + 64; ++j) {
    int hh = j >> 7, k = j & 127;
    float tv = 0.f;
#pragma unroll
    for (int sl = 0; sl < 8; ++sl)
      tv += Totp2[(size_t)((b * 8 + hh) * 8 + sl) * 128 + k];
    s += tv * wo[(size_t)j * 128 + c];
  }
  if (h2) sh[c] = s;
  __syncthreads();
  if (!h2) Totp[(size_t)(b * 8 + g) * 128 + c] = s + sh[c];
}

// ---------------- 8) Attention: barrier-free, dbuf-staged, 4 blocks/CU ---------
// grid 1024 x 256 thr (4 waves). xcd=bid&7: b=xcd>>1, tcA=xcd&1. slot=bid>>3 in
// [0,128): tcB=slot&7, q=slot>>3. tc=2*tcB+tcA in [0,16); tiles tt ≡ tc mod 16.
// Wave w: phases st=4q+w, 127-st. Per head: batch-load K/Q (VW) into dbuf regs,
// MFMA previous head's — latency hides under MFMAs + 4 waves/SIMD TLP.
__global__ __launch_bounds__(256, 4) void k_attn(const unsigned char* __restrict__ Qf,
                                                 const unsigned char* __restrict__ Kf,
                                                 const _Float16* __restrict__ VWf,
                                                 unsigned char* __restrict__ Part) {
  int tid = threadIdx.x;
  int w = tid >> 6, lane = tid & 63, lr = lane & 15, lg = lane >> 4;
  int bid = blockIdx.x;
  int xcd = bid & 7, slot = bid >> 3;
  int b = xcd >> 1, tcA = xcd & 1;
  int tcB = slot & 7, q = slot >> 3;
  int tc = (tcB << 1) | tcA;                  // [0,16)
  const float SC = 0.001953125f;              // 1/(16*32)
  const size_t BH = (size_t)SEQ * HDIM;
  const size_t PSZ = (size_t)NBATCH * SEQ * HDIM;  // 1 MB per tc slot

#pragma unroll 1
  for (int ph = 0; ph < 2; ++ph) {
    int st = ph ? (127 - (q * 4 + w)) : (q * 4 + w);
    int rb = st * 16;

    f32x4 oa[8];
#pragma unroll
    for (int cf = 0; cf < 8; ++cf) oa[cf] = (f32x4){0.f, 0.f, 0.f, 0.f};

    int ttF = 112 + tc;
#pragma unroll 1
    for (int tt = ttF; tt >= st; tt -= 16) {
      int t0 = tt * 16;
      const unsigned char* Kb = Kf + (size_t)(t0 + lr) * HDIM + lg * 8;
      const unsigned char* Qb = Qf + (size_t)(rb + lr) * HDIM + lg * 8;

      // ---- QK, per-head dbuf: load h+1 while computing h ----
      f32x4 S[8];
      i64 kfb[2][4], qfb[2][4];
#pragma unroll
      for (int ks = 0; ks < 4; ++ks) {
        kfb[0][ks] = *reinterpret_cast<const i64*>(Kb + (size_t)(b * 8) * BH + ks * 32);
        qfb[0][ks] = *reinterpret_cast<const i64*>(Qb + (size_t)(b * 8) * BH + ks * 32);
      }
#pragma unroll
      for (int h = 0; h < 8; ++h) {
        int cb = h & 1, nb = cb ^ 1;
        if (h < 7) {
#pragma unroll
          for (int ks = 0; ks < 4; ++ks) {
            kfb[nb][ks] = *reinterpret_cast<const i64*>(Kb + (size_t)(b * 8 + h + 1) * BH + ks * 32);
            qfb[nb][ks] = *reinterpret_cast<const i64*>(Qb + (size_t)(b * 8 + h + 1) * BH + ks * 32);
          }
        }
        f32x4 s = (f32x4){0.f, 0.f, 0.f, 0.f};
#pragma unroll
        for (int ks = 0; ks < 4; ++ks)
          s = __builtin_amdgcn_mfma_f32_16x16x32_fp8_fp8(kfb[cb][ks], qfb[cb][ks], s, 0, 0, 0);
        S[h] = s;
      }

      // ---- cross-head softmax: fully in-register ----
      f16x4 P[8];
      {
        float sm0 = 0.f, sm1 = 0.f, sm2 = 0.f, sm3 = 0.f;
#pragma unroll
        for (int h = 0; h < 8; ++h) {
          S[h][0] = __expf(S[h][0] * SC); sm0 += S[h][0];
          S[h][1] = __expf(S[h][1] * SC); sm1 += S[h][1];
          S[h][2] = __expf(S[h][2] * SC); sm2 += S[h][2];
          S[h][3] = __expf(S[h][3] * SC); sm3 += S[h][3];
        }
        int sg = rb + lr;
        int tb = t0 + 4 * lg;
        float i0 = 8.0f / sm0, i1 = 8.0f / sm1, i2 = 8.0f / sm2, i3 = 8.0f / sm3;
        bool m0 = (tb >= sg), m1 = (tb + 1 >= sg), m2 = (tb + 2 >= sg), m3 = (tb + 3 >= sg);
#pragma unroll
        for (int h = 0; h < 8; ++h) {
          float p0 = m0 ? S[h][0] * i0 - 1.0f : 0.0f;
          float p1 = m1 ? S[h][1] * i1 - 1.0f : 0.0f;
          float p2 = m2 ? S[h][2] * i2 - 1.0f : 0.0f;
          float p3 = m3 ? S[h][3] * i3 - 1.0f : 0.0f;
          P[h] = pack4h(__builtin_amdgcn_cvt_pkrtz(p0, p1),
                        __builtin_amdgcn_cvt_pkrtz(p2, p3));
        }
      }

      // ---- PV, per-head dbuf: load VW(h+1) while MFMAing h ----
      const _Float16* VWb = VWf + (size_t)tt * (128 * 16) + (size_t)lr * 16 + 4 * lg;
      i64 vwb[2][8];
#pragma unroll
      for (int cf = 0; cf < 8; ++cf)
        vwb[0][cf] = *reinterpret_cast<const i64*>(VWb + (size_t)(b * 8) * (128 * (size_t)(128 * 16) / 128) * 128 + (size_t)cf * 16 * 16);
      // NOTE: head stride in VWf is 128 tiles * 128*16 elems = (size_t)128*128*16
#pragma unroll
      for (int h = 0; h < 8; ++h) {
        int cb = h & 1, nb = cb ^ 1;
        if (h < 7) {
          const _Float16* VWn = VWb + (size_t)(b * 8 + h + 1) * ((size_t)128 * 128 * 16);
#pragma unroll
          for (int cf = 0; cf < 8; ++cf)
            vwb[nb][cf] = *reinterpret_cast<const i64*>(VWn + (size_t)cf * 256);
        }
        __builtin_amdgcn_s_setprio(1);
#pragma unroll
        for (int cf = 0; cf < 8; ++cf)
          oa[cf] = __builtin_amdgcn_mfma_f32_16x16x16f16(as_f16x4(vwb[cb][cf]), P[h], oa[cf], 0, 0, 0);
        __builtin_amdgcn_s_setprio(0);
      }
    }

    // flush: D[c_local=4lg+r][s_local=lr]; oa = 8*dev_slot; Part = dev_slot*32
    unsigned char* Pt = Part + (size_t)tc * PSZ + ((size_t)(b * SEQ + rb + lr)) * 128;
#pragma unroll
    for (int cf = 0; cf < 8; ++cf) {
      unsigned u = cvt_pk_fp8(oa[cf][0] * 4.0f, oa[cf][1] * 4.0f) |
                   (cvt_pk_fp8(oa[cf][2] * 4.0f, oa[cf][3] * 4.0f) << 16);
      *reinterpret_cast<unsigned*>(Pt + cf * 16 + lg * 4) = u;
    }
  }
}

// ---------------- 9) Finish: out = sum16(Part)/32 + sum8(Totp)/8 + b_o ---------
__global__ __launch_bounds__(256) void k_fin(const unsigned char* __restrict__ Part,
                                             const float* __restrict__ Totp,
                                             const float* __restrict__ bo,
                                             float* __restrict__ out) {
  __shared__ float lut[256];
  {
    int t = threadIdx.x;
    unsigned e = (t >> 3) & 15u, m = t & 7u;
    float mag = e ? ldexpf((float)(8 + m), (int)e - 10) : ldexpf((float)m, -9);
    lut[t] = (t & 128) ? -mag : mag;
  }
  __syncthreads();
  const size_t PSZ = (size_t)NBATCH * SEQ * HDIM;
  int idx = blockIdx.x * 256 + threadIdx.x;  // 1M elements
  int c = idx & 127, sg = idx >> 7;
  int b = sg >> 11;
  float s = 0.f;
#pragma unroll
  for (int t = 0; t < 16; ++t) s += lut[Part[(size_t)t * PSZ + (size_t)sg * 128 + c]];
  float tw = 0.f;
#pragma unroll
  for (int g = 0; g < 8; ++g) tw += Totp[(size_t)(b * 8 + g) * 128 + c];
  out[(size_t)sg * 128 + c] = s * 0.03125f + tw * 0.125f + bo[c];
}

extern "C" void kernel_launch(void* const* d_in, const int* in_sizes, int n_in,
                              void* d_out, int out_size, void* d_ws, size_t ws_size,
                              hipStream_t stream) {
  const float* x    = (const float*)d_in[0];
  const float* wqkv = (const float*)d_in[1];
  const float* bqkv = (const float*)d_in[2];
  const float* wo   = (const float*)d_in[3];
  const float* bo   = (const float*)d_in[4];

  char* ws = (char*)d_ws;
  const size_t MB = (size_t)1 << 20;
  short* xb           = (short*)(ws + 0);               //  2 MB : x bf16
  short* wqt          = (short*)(ws + 2 * MB);          // .75MB : W_qkv^T bf16
  short* wot          = (short*)(ws + 3 * MB);          // .25MB : W_o^T bf16
  unsigned char* Qf   = (unsigned char*)(ws + 4 * MB);  //  8 MB fp8 [bh][s][c]
  unsigned char* Kf   = (unsigned char*)(ws + 12 * MB); //  8 MB fp8 [bh][t][c]
  short* Vb           = (short*)(ws + 20 * MB);         // 16 MB bf16 (dead after k_tot)
  _Float16* VWf       = (_Float16*)(ws + 36 * MB);      // 16 MB f16 [bh][t/16][c][16]
  float* Totp2        = (float*)(ws + 52 * MB);         // 128 KB [bh][slice][c]
  float* Totp         = (float*)(ws + 52 * MB + 256 * 1024); // 16 KB [b][g][c]
  unsigned char* Part = (unsigned char*)(ws + 20 * MB); // 16 MB fp8 x16 (aliases Vb)

  hipLaunchKernelGGL(k_cvt_x, dim3(512), dim3(256), 0, stream, x, xb);
  hipLaunchKernelGGL(k_wqkv, dim3(1536), dim3(256), 0, stream, wqkv, wqt);
  hipLaunchKernelGGL(k_wo, dim3(512), dim3(256), 0, stream, wo, wot);
  hipLaunchKernelGGL(k_qkv, dim3(24, 128), dim3(256), 0, stream, xb, wqt, bqkv, Qf, Kf, Vb);
  hipLaunchKernelGGL(k_vw, dim3(32, 32), dim3(256), 0, stream, wot, Vb, VWf);
  hipLaunchKernelGGL(k_tot, dim3(32, 8), dim3(256), 0, stream, Vb, Totp2);
  hipLaunchKernelGGL(k_totw, dim3(4, 8), dim3(256), 0, stream, Totp2, wo, Totp);
  hipLaunchKernelGGL(k_attn, dim3(1024), dim3(256), 0, stream, Qf, Kf, VWf, Part);
  hipLaunchKernelGGL(k_fin, dim3(4096), dim3(256), 0, stream, Part, Totp, bo, (float*)d_out);
}

// Round 12
// 293.309 us; speedup vs baseline: 1.9995x; 1.2852x over previous
//
#include <hip/hip_runtime.h>
#include <hip/hip_bf16.h>

// Problem constants: B=4, S=2048, HID=128, NH=8, D_MODEL=1024
#define SEQ 2048
#define NBATCH 4
#define NHEAD 8
#define HDIM 128

typedef __attribute__((ext_vector_type(8))) short bf16x8;
typedef __attribute__((ext_vector_type(4))) float f32x4;
typedef long i64;
typedef unsigned long long u64;

static __device__ __forceinline__ short f2b(float f) {
  union { float f; unsigned u; } v; v.f = f;
  unsigned r = (v.u + 0x7FFFu + ((v.u >> 16) & 1u)) >> 16;
  return (short)(unsigned short)r;
}
static __device__ __forceinline__ float b2f(short b) {
  union { unsigned u; float f; } v; v.u = ((unsigned)(unsigned short)b) << 16;
  return v.f;
}
// OCP e4m3fn encode (software fallback), RTN-even, saturate at 448.
static __device__ __forceinline__ unsigned f2e4m3(float x) {
  union { float f; unsigned u; } v; v.f = x;
  unsigned s = (v.u >> 24) & 0x80u;
  unsigned a = v.u & 0x7FFFFFFFu;
  if (a > 0x43E00000u) a = 0x43E00000u;
  if (a < 0x3C800000u) {
    union { unsigned u; float f; } w; w.u = a;
    return s | (unsigned)(int)(w.f * 512.0f + 0.5f);
  }
  a += 0x7FFFFu + ((a >> 20) & 1u);
  return s | (((a >> 23) - 120u) << 3) | ((a >> 20) & 7u);
}

#if defined(__has_builtin)
#if __has_builtin(__builtin_amdgcn_cvt_pk_fp8_f32)
#define HAVE_HW_FP8 1
#endif
#endif
static __device__ __forceinline__ unsigned cvt_pk_fp8(float a, float b) {
#ifdef HAVE_HW_FP8
  return (unsigned)__builtin_amdgcn_cvt_pk_fp8_f32(a, b, 0, false) & 0xFFFFu;
#else
  return f2e4m3(a) | (f2e4m3(b) << 8);
#endif
}
static __device__ __forceinline__ unsigned cvt_fp8_1(float a) {
  return cvt_pk_fp8(a, 0.0f) & 0xFFu;
}

// raw barrier: drain own LDS ops, then s_barrier. Global loads stay in flight.
#define BARRIER_RAW() asm volatile("s_waitcnt lgkmcnt(0)\n\ts_barrier" ::: "memory")

// ---------------- 1) x fp32 -> bf16 ----------------
__global__ __launch_bounds__(256) void k_cvt_x(const float* __restrict__ x,
                                               short* __restrict__ xb) {
  int i = blockIdx.x * blockDim.x + threadIdx.x;
  const float4* p = reinterpret_cast<const float4*>(x) + (size_t)i * 2;
  float4 a = p[0], c = p[1];
  bf16x8 o;
  o[0] = f2b(a.x); o[1] = f2b(a.y); o[2] = f2b(a.z); o[3] = f2b(a.w);
  o[4] = f2b(c.x); o[5] = f2b(c.y); o[6] = f2b(c.z); o[7] = f2b(c.w);
  reinterpret_cast<bf16x8*>(xb)[i] = o;
}

// ---------------- 2) W_qkv [128][3072] -> Wqt bf16 [3072][128] ----------------
__global__ __launch_bounds__(256) void k_wqkv(const float* __restrict__ w,
                                              short* __restrict__ wt) {
  int tid = blockIdx.x * blockDim.x + threadIdx.x;
  int k = tid & 127, j = tid >> 7;
  wt[tid] = f2b(w[(size_t)k * 3072 + j]);
}

// ---------------- 3) W_o [1024][128] -> Wot bf16 [128][1024] ----------------
__global__ __launch_bounds__(256) void k_wo(const float* __restrict__ w,
                                            short* __restrict__ wt) {
  int tid = blockIdx.x * blockDim.x + threadIdx.x;
  int k = tid & 1023, c = tid >> 10;
  wt[tid] = f2b(w[(size_t)k * 128 + c]);
}

// ---------------- 4) QKV GEMM -> Qf,Kf fp8 (x4) [bh][s][c]; Vb bf16 [bh][t][c] -
__global__ __launch_bounds__(256) void k_qkv(const short* __restrict__ xb,
                                             const short* __restrict__ wqt,
                                             const float* __restrict__ bias,
                                             unsigned char* __restrict__ Qf,
                                             unsigned char* __restrict__ Kf,
                                             short* __restrict__ Vb) {
  int wave = threadIdx.x >> 6, lane = threadIdx.x & 63;
  int lr = lane & 15, lg = lane >> 4;
  int m0 = blockIdx.y * 64 + wave * 16;
  int j0 = blockIdx.x * 128;

  bf16x8 a[4];
#pragma unroll
  for (int ks = 0; ks < 4; ++ks)
    a[ks] = *reinterpret_cast<const bf16x8*>(xb + (size_t)(m0 + lr) * 128 + ks * 32 + lg * 8);

  f32x4 acc[8];
#pragma unroll
  for (int nf = 0; nf < 8; ++nf) acc[nf] = (f32x4){0.f, 0.f, 0.f, 0.f};

#pragma unroll
  for (int ks = 0; ks < 4; ++ks) {
#pragma unroll
    for (int nf = 0; nf < 8; ++nf) {
      bf16x8 bfr = *reinterpret_cast<const bf16x8*>(
          wqt + (size_t)(j0 + nf * 16 + lr) * 128 + ks * 32 + lg * 8);
      acc[nf] = __builtin_amdgcn_mfma_f32_16x16x32_bf16(a[ks], bfr, acc[nf], 0, 0, 0);
    }
  }

  int bb = m0 >> 11;
  int sbase = m0 & 2047;
#pragma unroll
  for (int nf = 0; nf < 8; ++nf) {
    int j = j0 + nf * 16 + lr;
    float bv = bias[j];
    int sel = j >> 10;
    int jj = j & 1023;
    int h = jj >> 7, c = jj & 127;
    size_t bh = (size_t)(bb * NHEAD + h);
    if (sel == 2) {
#pragma unroll
      for (int r = 0; r < 4; ++r) {
        int s = sbase + lg * 4 + r;
        Vb[(bh * SEQ + s) * HDIM + c] = f2b(acc[nf][r] + bv);
      }
    } else {
      unsigned char* dst = (sel ? Kf : Qf);
#pragma unroll
      for (int r = 0; r < 4; ++r) {
        int s = sbase + lg * 4 + r;
        dst[(bh * SEQ + s) * HDIM + c] = (unsigned char)cvt_fp8_1((acc[nf][r] + bv) * 4.0f);
      }
    }
  }
}

// ---------------- 5) VW8 = 32 * (V @ W_o[head]) -> fp8 [bh][c][t] ---------------
__global__ __launch_bounds__(256) void k_vw(const short* __restrict__ wot,
                                            const short* __restrict__ Vb,
                                            unsigned char* __restrict__ VW8) {
  int w = threadIdx.x >> 6, lane = threadIdx.x & 63, lr = lane & 15, lg = lane >> 4;
  int bh = blockIdx.y, h = bh & 7;
  int tile = blockIdx.x * 4 + w;
  int t0 = tile * 16;

  f32x4 acc[8];
#pragma unroll
  for (int cf = 0; cf < 8; ++cf) acc[cf] = (f32x4){0.f, 0.f, 0.f, 0.f};

#pragma unroll
  for (int ks = 0; ks < 4; ++ks) {
    bf16x8 bfr = *reinterpret_cast<const bf16x8*>(
        Vb + ((size_t)bh * SEQ + t0 + lr) * HDIM + ks * 32 + lg * 8);
#pragma unroll
    for (int cf = 0; cf < 8; ++cf) {
      bf16x8 af = *reinterpret_cast<const bf16x8*>(
          wot + (size_t)(cf * 16 + lr) * 1024 + h * 128 + ks * 32 + lg * 8);
      acc[cf] = __builtin_amdgcn_mfma_f32_16x16x32_bf16(af, bfr, acc[cf], 0, 0, 0);
    }
  }
  // D[c_local=4lg+r][t_local=lr] -> VW8[bh][c][t0+lr], value x32
  unsigned char* dst = VW8 + (size_t)bh * HDIM * SEQ;
#pragma unroll
  for (int cf = 0; cf < 8; ++cf)
#pragma unroll
    for (int r = 0; r < 4; ++r)
      dst[(size_t)(cf * 16 + 4 * lg + r) * SEQ + t0 + lr] =
          (unsigned char)cvt_fp8_1(acc[cf][r] * 32.0f);
}

// ---------------- 6) Totp2[bh][slice][c] = sum over 256 rows of Vb -------------
__global__ __launch_bounds__(256) void k_tot(const short* __restrict__ Vb,
                                             float* __restrict__ Totp2) {
  __shared__ float sh[16][128];
  int bh = blockIdx.x, sl = blockIdx.y;
  int i = threadIdx.x & 15, g = threadIdx.x >> 4;
  const short* p = Vb + (size_t)bh * SEQ * HDIM + i * 8;
  float s[8] = {0, 0, 0, 0, 0, 0, 0, 0};
  for (int r = sl * 256 + g; r < sl * 256 + 256; r += 16) {
    bf16x8 v = *reinterpret_cast<const bf16x8*>(p + (size_t)r * HDIM);
#pragma unroll
    for (int j = 0; j < 8; ++j) s[j] += b2f(v[j]);
  }
#pragma unroll
  for (int j = 0; j < 8; ++j) sh[g][i * 8 + j] = s[j];
  __syncthreads();
  if (threadIdx.x < 128) {
    float t = 0;
#pragma unroll
    for (int g2 = 0; g2 < 16; ++g2) t += sh[g2][threadIdx.x];
    Totp2[(size_t)(bh * 8 + sl) * 128 + threadIdx.x] = t;
  }
}

// ---------------- 7) Totp[b][g][c] = sum_{j in g-range} Totv(j) * W_o[j][c] ----
__global__ __launch_bounds__(256) void k_totw(const float* __restrict__ Totp2,
                                              const float* __restrict__ wo,
                                              float* __restrict__ Totp) {
  __shared__ float sh[128];
  int b = blockIdx.x, g = blockIdx.y;       // grid (4,8)
  int c = threadIdx.x & 127, h2 = threadIdx.x >> 7;
  float s = 0.f;
  int j0 = g * 128 + h2 * 64;
  for (int j = j0; j < j0 + 64; ++j) {
    int hh = j >> 7, k = j & 127;
    float tv = 0.f;
#pragma unroll
    for (int sl = 0; sl < 8; ++sl)
      tv += Totp2[(size_t)((b * 8 + hh) * 8 + sl) * 128 + k];
    s += tv * wo[(size_t)j * 128 + c];
  }
  if (h2) sh[c] = s;
  __syncthreads();
  if (!h2) Totp[(size_t)(b * 8 + g) * 128 + c] = s + sh[c];
}

// ---------------- 8) Attention: 16 waves, 64-row chunks, W_o-folded PV ---------
// grid 256, 1024 thr = 16 waves: wave (h = w&7, g2 = w>>3). Per step (t-tile 32):
//  QK: wave computes S[64 s][16 t] of its t-half (g2) -> Sm[h]    (8 regs kf)
//  softmax: 1024 thr x 2 positions, cross-head via Sm -> Pm fp8
//  PV: wave computes out[64 s][64 c] of its c-half (g2) with VW8  (oa[4][4]=64)
// bid: xcd=bid&7 -> b=xcd>>1, tcA=xcd&1; slot=bid>>3: p=slot>>1, tcB=slot&1;
// tc=2*tcB+tcA in [0,4); tiles tt ≡ tc mod 4 desc; chunks {p, 31-p}.
// Per-wave regs ~120 <= 128 cap of (1024,4): no spills, 4 waves/SIMD.
__global__ __launch_bounds__(1024, 4) void k_attn(const unsigned char* __restrict__ Qf,
                                                  const unsigned char* __restrict__ Kf,
                                                  const unsigned char* __restrict__ VW8,
                                                  unsigned char* __restrict__ Part) {
  __shared__ float Sm[8][64][36];          // raw QK^T (x16 scaled) f32 (72 KB)
  __shared__ unsigned char Pm[8][64][40];  // P8 = 8*alpha-1 fp8        (20 KB)

  const size_t PSZ = (size_t)NBATCH * SEQ * HDIM;  // 1 MB per slot
  const size_t BH = (size_t)SEQ * HDIM;
  int tid = threadIdx.x;
  int wu = __builtin_amdgcn_readfirstlane(tid) >> 6;  // wave id 0..15 (SGPR)
  int h = wu & 7, g2 = wu >> 3;
  int lane = tid & 63, lr = lane & 15, lg = lane >> 4;
  int bid = blockIdx.x;
  int xcd = bid & 7, slot = bid >> 3;
  int b = xcd >> 1, tcA = xcd & 1;
  int p = slot >> 1, tcB = slot & 1;
  int tc = tcB * 2 + tcA;

  const unsigned char* Qh = Qf + (size_t)(b * NHEAD + h) * BH;
  const unsigned char* Kh = Kf + (size_t)(b * NHEAD + h) * BH;
  const unsigned char* Vh = VW8 + (size_t)(b * NHEAD + h) * BH;  // [c][t]

  int sl = tid >> 4;             // softmax row 0..63
  int t2 = (tid & 15) * 2;       // softmax col base (2 cols/thread)
  const float SC = 0.001953125f; // 1/(16*32): undo Q*4,K*4 and /sqrt(1024)

#pragma unroll 1
  for (int ph = 0; ph < 2; ++ph) {
    int c0 = ph ? (31 - p) : p;
    int rb = c0 * 64;

    // Q A-frags: 64 rows, held across the K-loop (32 regs)
    i64 qa[4][4];
#pragma unroll
    for (int rf = 0; rf < 4; ++rf)
#pragma unroll
      for (int ks = 0; ks < 4; ++ks)
        qa[rf][ks] = *reinterpret_cast<const i64*>(
            Qh + (size_t)(rb + rf * 16 + lr) * HDIM + ks * 32 + lg * 8);

    f32x4 oa[4][4];
#pragma unroll
    for (int rf = 0; rf < 4; ++rf)
#pragma unroll
      for (int cf = 0; cf < 4; ++cf) oa[rf][cf] = (f32x4){0.f, 0.f, 0.f, 0.f};

    int ttF = 60 + tc, ttMin = 2 * c0;

#pragma unroll 1
    for (int tt = ttF; tt >= ttMin; tt -= 4) {
      int t0 = tt * 32;

      // ---- K loads: this wave's t-half (16 rows), 8 regs ----
      i64 kf[4];
#pragma unroll
      for (int ks = 0; ks < 4; ++ks)
        kf[ks] = *reinterpret_cast<const i64*>(
            Kh + (size_t)(t0 + g2 * 16 + lr) * HDIM + ks * 32 + lg * 8);

      // ---- QK^T -> Sm[h][s][g2-half] (16 MFMAs) ----
      __builtin_amdgcn_s_setprio(1);
#pragma unroll
      for (int rf = 0; rf < 4; ++rf) {
        f32x4 s = (f32x4){0.f, 0.f, 0.f, 0.f};
#pragma unroll
        for (int ks = 0; ks < 4; ++ks)
          s = __builtin_amdgcn_mfma_f32_16x16x32_fp8_fp8(qa[rf][ks], kf[ks], s, 0, 0, 0);
        int rowb = rf * 16 + lg * 4;
#pragma unroll
        for (int r = 0; r < 4; ++r) Sm[h][rowb + r][g2 * 16 + lr] = s[r];
      }
      __builtin_amdgcn_s_setprio(0);
      BARRIER_RAW();

      // ---- VW8 loads for PV (issued early; used after next barrier) ----
      i64 vf[4];
#pragma unroll
      for (int cf = 0; cf < 4; ++cf)
        vf[cf] = *reinterpret_cast<const i64*>(
            Vh + (size_t)(g2 * 64 + cf * 16 + lr) * SEQ + t0 + lg * 8);

      // ---- cross-head softmax: 2 positions/thread ----
      {
        int sg = rb + sl;
        int tg = t0 + t2;
        float e[8][2];
        float sm0 = 0.f, sm1 = 0.f;
#pragma unroll
        for (int hh = 0; hh < 8; ++hh) {
          float2 v = *reinterpret_cast<const float2*>(&Sm[hh][sl][t2]);
          e[hh][0] = __expf(v.x * SC); sm0 += e[hh][0];
          e[hh][1] = __expf(v.y * SC); sm1 += e[hh][1];
        }
        float inv0 = 8.0f / sm0, inv1 = 8.0f / sm1;
        bool mk0 = (tg >= sg), mk1 = (tg + 1 >= sg);
#pragma unroll
        for (int hh = 0; hh < 8; ++hh) {
          float a0 = mk0 ? (e[hh][0] * inv0 - 1.0f) : 0.0f;
          float a1 = mk1 ? (e[hh][1] * inv1 - 1.0f) : 0.0f;
          *reinterpret_cast<unsigned short*>(&Pm[hh][sl][t2]) =
              (unsigned short)cvt_pk_fp8(a0, a1);
        }
      }
      BARRIER_RAW();

      // ---- PV: out[64 s][64 c] of this wave's c-half (16 MFMAs) ----
      __builtin_amdgcn_s_setprio(1);
#pragma unroll
      for (int rf = 0; rf < 4; ++rf) {
        i64 pa = *reinterpret_cast<const i64*>(&Pm[h][rf * 16 + lr][lg * 8]);
#pragma unroll
        for (int cf = 0; cf < 4; ++cf)
          oa[rf][cf] = __builtin_amdgcn_mfma_f32_16x16x32_fp8_fp8(pa, vf[cf], oa[rf][cf], 0, 0, 0);
      }
      __builtin_amdgcn_s_setprio(0);
    }

    // flush: oa = 256*dev_slot -> store fp8(32*dev) into slot (h*4+tc)
    unsigned char* Pt = Part + (size_t)(h * 4 + tc) * PSZ +
                        ((size_t)(b * SEQ + rb)) * 128 + g2 * 64;
#pragma unroll
    for (int rf = 0; rf < 4; ++rf)
#pragma unroll
      for (int cf = 0; cf < 4; ++cf)
#pragma unroll
        for (int r = 0; r < 4; ++r)
          Pt[(size_t)(rf * 16 + 4 * lg + r) * 128 + cf * 16 + lr] =
              (unsigned char)cvt_fp8_1(oa[rf][cf][r] * 0.125f);
  }
}

// ---------------- 9) Finish: out = sum32(Part)/32 + sum8(Totp)/8 + b_o ---------
__global__ __launch_bounds__(256) void k_fin(const unsigned char* __restrict__ Part,
                                             const float* __restrict__ Totp,
                                             const float* __restrict__ bo,
                                             float* __restrict__ out) {
  __shared__ float lut[256];
  {
    int t = threadIdx.x;
    unsigned e = (t >> 3) & 15u, m = t & 7u;
    float mag = e ? ldexpf((float)(8 + m), (int)e - 10) : ldexpf((float)m, -9);
    lut[t] = (t & 128) ? -mag : mag;
  }
  __syncthreads();
  const size_t PSZ = (size_t)NBATCH * SEQ * HDIM;
  int idx = blockIdx.x * 256 + threadIdx.x;  // 1M elements
  int c = idx & 127, sg = idx >> 7;
  int b = sg >> 11;
  float s = 0.f;
#pragma unroll
  for (int t = 0; t < 32; ++t) s += lut[Part[(size_t)t * PSZ + (size_t)sg * 128 + c]];
  float tw = 0.f;
#pragma unroll
  for (int g = 0; g < 8; ++g) tw += Totp[(size_t)(b * 8 + g) * 128 + c];
  out[(size_t)sg * 128 + c] = s * 0.03125f + tw * 0.125f + bo[c];
}

extern "C" void kernel_launch(void* const* d_in, const int* in_sizes, int n_in,
                              void* d_out, int out_size, void* d_ws, size_t ws_size,
                              hipStream_t stream) {
  const float* x    = (const float*)d_in[0];
  const float* wqkv = (const float*)d_in[1];
  const float* bqkv = (const float*)d_in[2];
  const float* wo   = (const float*)d_in[3];
  const float* bo   = (const float*)d_in[4];

  char* ws = (char*)d_ws;
  const size_t MB = (size_t)1 << 20;
  short* xb           = (short*)(ws + 0);               //  2 MB : x bf16
  short* wqt          = (short*)(ws + 2 * MB);          // .75MB : W_qkv^T bf16
  short* wot          = (short*)(ws + 3 * MB);          // .25MB : W_o^T bf16
  unsigned char* Qf   = (unsigned char*)(ws + 4 * MB);  //  8 MB fp8 [bh][s][c]
  unsigned char* Kf   = (unsigned char*)(ws + 12 * MB); //  8 MB fp8 [bh][t][c]
  short* Vb           = (short*)(ws + 20 * MB);         // 16 MB bf16 (dead after k_vw/k_tot)
  unsigned char* Part = (unsigned char*)(ws + 20 * MB); // 32 MB fp8 x32 (aliases Vb)
  unsigned char* VW8  = (unsigned char*)(ws + 52 * MB); //  8 MB fp8 [bh][c][t]
  float* Totp2        = (float*)(ws + 60 * MB);         // 128 KB [bh][slice][c]
  float* Totp         = (float*)(ws + 60 * MB + 256 * 1024); // 16 KB [b][g][c]

  hipLaunchKernelGGL(k_cvt_x, dim3(512), dim3(256), 0, stream, x, xb);
  hipLaunchKernelGGL(k_wqkv, dim3(1536), dim3(256), 0, stream, wqkv, wqt);
  hipLaunchKernelGGL(k_wo, dim3(512), dim3(256), 0, stream, wo, wot);
  hipLaunchKernelGGL(k_qkv, dim3(24, 128), dim3(256), 0, stream, xb, wqt, bqkv, Qf, Kf, Vb);
  hipLaunchKernelGGL(k_vw, dim3(32, 32), dim3(256), 0, stream, wot, Vb, VW8);
  hipLaunchKernelGGL(k_tot, dim3(32, 8), dim3(256), 0, stream, Vb, Totp2);
  hipLaunchKernelGGL(k_totw, dim3(4, 8), dim3(256), 0, stream, Totp2, wo, Totp);
  hipLaunchKernelGGL(k_attn, dim3(256), dim3(1024), 0, stream, Qf, Kf, VW8, Part);
  hipLaunchKernelGGL(k_fin, dim3(4096), dim3(256), 0, stream, Part, Totp, bo, (float*)d_out);
}